// Round 4
// baseline (739.932 us; speedup 1.0000x reference)
//
#include <hip/hip_runtime.h>
#include <hip/hip_bf16.h>

#define F 128

typedef __attribute__((ext_vector_type(8))) short short8;    // 8 bf16 = 4 VGPRs
typedef __attribute__((ext_vector_type(4))) float floatx4;   // MFMA C/D

__device__ __forceinline__ float bf_lo(unsigned u) { return __uint_as_float(u << 16); }
__device__ __forceinline__ float bf_hi(unsigned u) { return __uint_as_float(u & 0xffff0000u); }

// fp32 -> bf16 bits, round-to-nearest-even
__device__ __forceinline__ unsigned short f2bf(float x) {
  unsigned u = __float_as_uint(x);
  u += 0x7fffu + ((u >> 16) & 1u);
  return (unsigned short)(u >> 16);
}

// -------- CSR build step 1: histogram of dst --------
__global__ __launch_bounds__(256) void k_count(const int* __restrict__ dst,
                                               int* __restrict__ A, int E) {
  int e = blockIdx.x * 256 + threadIdx.x;
  if (e < E) atomicAdd(&A[dst[e]], 1);
}

// -------- CSR build step 2: in-place exclusive scan (single block) --------
__global__ __launch_bounds__(256) void k_scan(int* __restrict__ A, int n) {
  __shared__ int wtot[4];
  int t = threadIdx.x, l = t & 63, w = t >> 6;
  int base = 0;
  for (int i0 = 0; i0 < n; i0 += 256) {
    int i = i0 + t;
    int v = (i < n) ? A[i] : 0;
    int acc = v;
#pragma unroll
    for (int off = 1; off < 64; off <<= 1) {
      int u = __shfl_up(acc, off);
      if (l >= off) acc += u;
    }
    if (l == 63) wtot[w] = acc;
    __syncthreads();
    int woff = 0, total = 0;
#pragma unroll
    for (int ww = 0; ww < 4; ++ww) {
      total += wtot[ww];
      if (ww < w) woff += wtot[ww];
    }
    if (i < n) A[i] = base + woff + (acc - v);
    base += total;
    __syncthreads();
  }
}

// -------- CSR build step 3: fill adjacency; A becomes row-end (inclusive) --------
__global__ __launch_bounds__(256) void k_fill(const int* __restrict__ srcT,
                                              const int* __restrict__ dst,
                                              int* __restrict__ A, int* __restrict__ adj, int E) {
  int e = blockIdx.x * 256 + threadIdx.x;
  if (e >= E) return;
  int s = srcT[e], d = dst[e];
  int slot = atomicAdd(&A[d], 1);
  adj[slot] = s;
}

// -------- weight prep: Wcat[256][128] bf16 = [Wl ; Wr] --------
__global__ __launch_bounds__(256) void k_prepw(const float* __restrict__ Wl,
                                               const float* __restrict__ Wr,
                                               unsigned short* __restrict__ Wcat) {
  int i = blockIdx.x * 256 + threadIdx.x;
  if (i >= 256 * F) return;
  int k = i >> 7, n = i & (F - 1);
  float v = (k < F) ? Wl[k * F + n] : Wr[(k - F) * F + n];
  Wcat[i] = f2bf(v);
}

// -------- fp32 -> bf16 convert (x -> xb) --------
__global__ __launch_bounds__(256) void k_cvt(const float* __restrict__ x,
                                             unsigned short* __restrict__ xb, int n4) {
  int i = blockIdx.x * 256 + threadIdx.x;
  if (i >= n4) return;
  float4 v = ((const float4*)x)[i];
  ushort4 o = make_ushort4(f2bf(v.x), f2bf(v.y), f2bf(v.z), f2bf(v.w));
  ((ushort4*)xb)[i] = o;
}

// -------- mean aggregation by gather: one wave per dst row; bf16 output --------
template <typename T>
__global__ __launch_bounds__(256) void k_gather(const T* __restrict__ xin,
                                                const int* __restrict__ A,
                                                const int* __restrict__ adj,
                                                unsigned short* __restrict__ aggb, int N) {
  int d = blockIdx.x * 4 + (threadIdx.x >> 6);
  if (d >= N) return;
  int l = threadIdx.x & 63;
  int e0 = (d == 0) ? 0 : A[d - 1];
  int e1 = A[d];
  int deg = e1 - e0;
  float2 acc = make_float2(0.f, 0.f);
  int ids = (e0 + l < e1) ? adj[e0 + l] : 0;
  int m = min(deg, 64);
  for (int j = 0; j < m; ++j) {
    int s = __shfl(ids, j);
    float2 v;
    if constexpr (sizeof(T) == 2) {
      unsigned u = ((const unsigned*)xin)[(size_t)s * 64 + l];
      v = make_float2(bf_lo(u), bf_hi(u));
    } else {
      v = ((const float2*)(xin + (size_t)s * F))[l];
    }
    acc.x += v.x;
    acc.y += v.y;
  }
  for (int e = e0 + 64; e < e1; ++e) {
    int s = adj[e];
    float2 v;
    if constexpr (sizeof(T) == 2) {
      unsigned u = ((const unsigned*)xin)[(size_t)s * 64 + l];
      v = make_float2(bf_lo(u), bf_hi(u));
    } else {
      v = ((const float2*)(xin + (size_t)s * F))[l];
    }
    acc.x += v.x;
    acc.y += v.y;
  }
  float inv = 1.0f / fmaxf((float)deg, 1.0f);
  unsigned out = (unsigned)f2bf(acc.x * inv) | ((unsigned)f2bf(acc.y * inv) << 16);
  ((unsigned*)aggb)[(size_t)d * 64 + l] = out;
}

// -------- MFMA gemm: h[N][128] = [aggb | xb] @ Wcat + bias, + BN stats --------
// 4 waves/block; wave w owns cols [32w, 32w+32) (2 col-tiles of 16).
// Per row-block: 64 rows = 4 row-tiles of 16. B fragments held in registers.
__global__ __launch_bounds__(256) void k_gemm(
    const unsigned short* __restrict__ aggb, const unsigned short* __restrict__ xb,
    const unsigned short* __restrict__ Wcat, const float* __restrict__ bias,
    float* __restrict__ hout, float* __restrict__ csum, float* __restrict__ csumsq,
    int N, int nRowBlocks) {
  const int w = threadIdx.x >> 6;
  const int l = threadIdx.x & 63;
  const int lm = l & 15;   // tile row (A) / tile col (B, C/D)
  const int lq = l >> 4;   // quad
  const int cbase = 32 * w;

  // B fragments: [ctile][kstep]; B[k = 32s + 8*lq + j][n = cbase + 16c + lm]
  short8 bfrag[2][8];
#pragma unroll
  for (int c = 0; c < 2; ++c) {
    int col = cbase + 16 * c + lm;
#pragma unroll
    for (int s = 0; s < 8; ++s) {
      int k0 = 32 * s + lq * 8;
      short8 f;
#pragma unroll
      for (int j = 0; j < 8; ++j) f[j] = (short)Wcat[(k0 + j) * F + col];
      bfrag[c][s] = f;
    }
  }
  float bcol0 = bias[cbase + lm];
  float bcol1 = bias[cbase + 16 + lm];
  float bsum0 = 0.f, bsum1 = 0.f, bsq0 = 0.f, bsq1 = 0.f;

  for (int rb = blockIdx.x; rb < nRowBlocks; rb += gridDim.x) {
    int r0 = rb * 64;
    floatx4 acc[4][2] = {};
#pragma unroll
    for (int t = 0; t < 4; ++t) {
      int r = r0 + 16 * t + lm;  // may exceed N: pad rows exist, stores guarded
      const unsigned short* arow = aggb + (size_t)r * F + lq * 8;
      const unsigned short* xrow = xb + (size_t)r * F + lq * 8;
      short8 af[8];
#pragma unroll
      for (int s = 0; s < 4; ++s) {
        af[s] = *(const short8*)(arow + 32 * s);
        af[s + 4] = *(const short8*)(xrow + 32 * s);
      }
#pragma unroll
      for (int s = 0; s < 8; ++s) {
        acc[t][0] = __builtin_amdgcn_mfma_f32_16x16x32_bf16(af[s], bfrag[0][s], acc[t][0], 0, 0, 0);
        acc[t][1] = __builtin_amdgcn_mfma_f32_16x16x32_bf16(af[s], bfrag[1][s], acc[t][1], 0, 0, 0);
      }
    }
#pragma unroll
    for (int t = 0; t < 4; ++t) {
#pragma unroll
      for (int c = 0; c < 2; ++c) {
        int col = cbase + 16 * c + lm;
        float bc = c ? bcol1 : bcol0;
#pragma unroll
        for (int g = 0; g < 4; ++g) {
          int row = r0 + 16 * t + lq * 4 + g;
          if (row < N) {
            float v = acc[t][c][g] + bc;
            hout[(size_t)row * F + col] = v;
            if (c) { bsum1 += v; bsq1 += v * v; }
            else   { bsum0 += v; bsq0 += v * v; }
          }
        }
      }
    }
  }
  atomicAdd(csum + cbase + lm, bsum0);
  atomicAdd(csumsq + cbase + lm, bsq0);
  atomicAdd(csum + cbase + 16 + lm, bsum1);
  atomicAdd(csumsq + cbase + 16 + lm, bsq1);
}

// -------- BN finalize --------
__global__ void k_bnstats(const float* __restrict__ sum, const float* __restrict__ sumsq,
                          const float* __restrict__ g, const float* __restrict__ be,
                          float* __restrict__ scale, float* __restrict__ shift, float invN) {
  int c = threadIdx.x;
  float mu = sum[c] * invN;
  float var = fmaxf(sumsq[c] * invN - mu * mu, 0.0f);
  float sc = g[c] * rsqrtf(var + 1e-5f);
  scale[c] = sc;
  shift[c] = be[c] - mu * sc;
}

// -------- BN apply + ReLU: fp32 h -> bf16 dst --------
__global__ __launch_bounds__(256) void k_bnrelu(const float* __restrict__ h,
                                                unsigned short* __restrict__ dst,
                                                const float* __restrict__ scale,
                                                const float* __restrict__ shift, int n4) {
  int i = blockIdx.x * 256 + threadIdx.x;
  if (i >= n4) return;
  float4 v = ((const float4*)h)[i];
  int g = i & 31;
  float4 sc = ((const float4*)scale)[g];
  float4 sh = ((const float4*)shift)[g];
  ushort4 o = make_ushort4(f2bf(fmaxf(fmaf(v.x, sc.x, sh.x), 0.f)),
                           f2bf(fmaxf(fmaf(v.y, sc.y, sh.y), 0.f)),
                           f2bf(fmaxf(fmaf(v.z, sc.z, sh.z), 0.f)),
                           f2bf(fmaxf(fmaf(v.w, sc.w, sh.w), 0.f)));
  ((ushort4*)dst)[i] = o;
}

// -------- final linear 128 -> 2 (bf16 input) --------
__global__ __launch_bounds__(256) void k_out(const unsigned short* __restrict__ h,
                                             const float* __restrict__ Wout,
                                             const float* __restrict__ bout,
                                             float* __restrict__ out, int N) {
  __shared__ float W0[F], W1[F];
  if (threadIdx.x < F) {
    W0[threadIdx.x] = Wout[threadIdx.x * 2];
    W1[threadIdx.x] = Wout[threadIdx.x * 2 + 1];
  }
  __syncthreads();
  int r = blockIdx.x * 256 + threadIdx.x;
  if (r >= N) return;
  float a0 = bout[0];
  float a1 = bout[1];
  const uint4* hr = (const uint4*)(h + (size_t)r * F);
#pragma unroll 4
  for (int q = 0; q < 16; ++q) {
    uint4 u = hr[q];
    float v[8] = {bf_lo(u.x), bf_hi(u.x), bf_lo(u.y), bf_hi(u.y),
                  bf_lo(u.z), bf_hi(u.z), bf_lo(u.w), bf_hi(u.w)};
#pragma unroll
    for (int j = 0; j < 8; ++j) {
      a0 += v[j] * W0[8 * q + j];
      a1 += v[j] * W1[8 * q + j];
    }
  }
  out[2 * r] = a0;
  out[2 * r + 1] = a1;
}

extern "C" void kernel_launch(void* const* d_in, const int* in_sizes, int n_in,
                              void* d_out, int out_size, void* d_ws, size_t ws_size,
                              hipStream_t stream) {
  const float* x   = (const float*)d_in[0];
  const int*   eix = (const int*)d_in[1];
  const float* Wl0 = (const float*)d_in[2];
  const float* Wr0 = (const float*)d_in[3];
  const float* b0  = (const float*)d_in[4];
  const float* g0  = (const float*)d_in[5];
  const float* be0 = (const float*)d_in[6];
  const float* Wl1 = (const float*)d_in[7];
  const float* Wr1 = (const float*)d_in[8];
  const float* b1  = (const float*)d_in[9];
  const float* g1  = (const float*)d_in[10];
  const float* be1 = (const float*)d_in[11];
  const float* Wo  = (const float*)d_in[12];
  const float* bo  = (const float*)d_in[13];

  int N = in_sizes[0] / F;     // 50000
  int E = in_sizes[1] / 2;     // 600000
  const int* src  = eix;
  const int* dstv = eix + E;

  int nRowBlocks = (N + 63) / 64;      // 782
  size_t Npad = (size_t)nRowBlocks * 64;  // 50048

  // ws layout: aggb bf16[Npad*F] | xb bf16[Npad*F] | Wcat0 | Wcat1 | stats(768 f32) | h f32[N*F]
  unsigned short* aggb  = (unsigned short*)d_ws;
  unsigned short* xb    = aggb + Npad * F;
  unsigned short* Wcat0 = xb + Npad * F;
  unsigned short* Wcat1 = Wcat0 + 256 * F;
  float* stats = (float*)(Wcat1 + 256 * F);   // sum0, sq0, sum1, sq1 (128 each)
  float* scale = stats + 512;
  float* shift = scale + F;
  float* h     = shift + F;                   // N*F fp32
  // aliases:
  int* A    = (int*)d_out;       // N ints; dead before k_out writes d_out
  int* temp = (int*)h;           // src copy; h dead until gemm0
  int* adj  = (int*)d_in[1];     // overwrites src half; src preserved in temp

  hipMemsetAsync(A, 0, (size_t)N * sizeof(int), stream);
  hipMemsetAsync(stats, 0, 768 * sizeof(float), stream);
  hipMemcpyAsync(temp, src, (size_t)E * sizeof(int), hipMemcpyDeviceToDevice, stream);

  // ---- CSR build (shared by both layers) ----
  k_count<<<(E + 255) / 256, 256, 0, stream>>>(dstv, A, E);
  k_scan<<<1, 256, 0, stream>>>(A, N);
  k_fill<<<(E + 255) / 256, 256, 0, stream>>>(temp, dstv, A, adj, E);

  // ---- weight prep + x conversion ----
  k_prepw<<<128, 256, 0, stream>>>(Wl0, Wr0, Wcat0);
  k_prepw<<<128, 256, 0, stream>>>(Wl1, Wr1, Wcat1);
  int n4 = N * F / 4;
  k_cvt<<<(n4 + 255) / 256, 256, 0, stream>>>(x, xb, n4);

  // ---- layer 0 ----
  k_gather<float><<<(N + 3) / 4, 256, 0, stream>>>(x, A, adj, aggb, N);
  k_gemm<<<512, 256, 0, stream>>>(aggb, xb, Wcat0, b0, h, stats, stats + 128, N, nRowBlocks);
  k_bnstats<<<1, 128, 0, stream>>>(stats, stats + 128, g0, be0, scale, shift, 1.0f / N);
  k_bnrelu<<<(n4 + 255) / 256, 256, 0, stream>>>(h, xb, scale, shift, n4);  // h0b -> xb

  // ---- layer 1 ----
  k_gather<unsigned short><<<(N + 3) / 4, 256, 0, stream>>>(xb, A, adj, aggb, N);
  k_gemm<<<512, 256, 0, stream>>>(aggb, xb, Wcat1, b1, h, stats + 256, stats + 384, N, nRowBlocks);
  k_bnstats<<<1, 128, 0, stream>>>(stats + 256, stats + 384, g1, be1, scale, shift, 1.0f / N);
  k_bnrelu<<<(n4 + 255) / 256, 256, 0, stream>>>(h, aggb, scale, shift, n4); // h1b -> aggb

  // ---- output head ----
  k_out<<<(N + 255) / 256, 256, 0, stream>>>(aggb, Wo, bo, (float*)d_out, N);
}